// Round 1
// baseline (603.190 us; speedup 1.0000x reference)
//
#include <hip/hip_runtime.h>
#include <hip/hip_cooperative_groups.h>

namespace cg = cooperative_groups;

// RFNorm: out = (0.5*groupnorm(x) + 0.5*tokennorm(x)) * weight + bias
// x: (B=8, T=4000, D=1024) fp32; G=5 contiguous groups of L=T/G tokens.
//
// R3: single cooperative kernel, 3 phases separated by grid.sync().
//   Phase 1: persistent waves, wave-stride over rows -> tstats[row]={sum,sumsq}
//   Phase 2: first B*G blocks reduce their group's L token-sums -> gstats
//   Phase 3: persistent blocks, block-stride over 4-row chunks, streaming apply
// Rationale: previous 3-kernel version was 4x off the 393 MB / 6.3 TB/s
// roofline (~62 us) with each kernel individually <77 us (hidden below reset
// fills in rocprof). Fusion removes 2 launch boundaries + the 40-block
// latency-bound greduce dispatch, and persistent waves pipeline HBM latency
// across loop iterations instead of one-shot waves.

#define EPS 1e-5f
#define NUM_G 5
#define NBLK 1024   // 256 CUs x 4 blocks/CU -- guaranteed co-resident
#define NTHR 256

__global__ __launch_bounds__(NTHR, 4) void rfnorm_fused(
    const float4* __restrict__ x,
    const float4* __restrict__ weight, const float4* __restrict__ bias,
    float4* __restrict__ out,
    float2* __restrict__ tstats, float2* __restrict__ gstats,
    int n_rows, int L, float invD, float invNg) {
  const int tid  = threadIdx.x;
  const int wave = tid >> 6, lane = tid & 63;

  // ---- Phase 1: per-row {sum, sumsq}; one wave per row, wave-stride ----
  const int n_waves = gridDim.x * (NTHR / 64);
  for (int row = blockIdx.x * (NTHR / 64) + wave; row < n_rows; row += n_waves) {
    const long base = (long)row * 256;
    float s = 0.f, sq = 0.f;
    #pragma unroll
    for (int j = 0; j < 4; ++j) {
      float4 v = x[base + lane + 64 * j];
      s  += (v.x + v.y) + (v.z + v.w);
      sq += (v.x * v.x + v.y * v.y) + (v.z * v.z + v.w * v.w);
    }
    #pragma unroll
    for (int off = 1; off < 64; off <<= 1) {
      s  += __shfl_xor(s,  off, 64);
      sq += __shfl_xor(sq, off, 64);
    }
    if (lane == 0) { float2 st; st.x = s; st.y = sq; tstats[row] = st; }
  }

  __threadfence();           // device-scope release: tstats visible cross-XCD
  cg::this_grid().sync();

  // ---- Phase 2: group reduce; first B*NUM_G (=40) blocks, one group each ----
  const int n_groups = n_rows / L;
  if ((int)blockIdx.x < n_groups) {
    const int g = blockIdx.x;
    float s = 0.f, sq = 0.f;
    for (int j = tid; j < L; j += NTHR) {
      float2 st = tstats[(long)g * L + j];
      s += st.x; sq += st.y;
    }
    #pragma unroll
    for (int off = 1; off < 64; off <<= 1) {
      s  += __shfl_xor(s,  off, 64);
      sq += __shfl_xor(sq, off, 64);
    }
    __shared__ float ls[4], lq[4];
    if (lane == 0) { ls[wave] = s; lq[wave] = sq; }
    __syncthreads();
    if (tid == 0) {
      const float S  = (ls[0] + ls[1]) + (ls[2] + ls[3]);
      const float SQ = (lq[0] + lq[1]) + (lq[2] + lq[3]);
      const float gmu = S * invNg;
      float2 o;
      o.x = gmu;
      o.y = rsqrtf(SQ * invNg - gmu * gmu + EPS) * 0.5f;  // fold RFN=0.5
      gstats[g] = o;
    }
  }

  __threadfence();           // gstats visible cross-XCD
  cg::this_grid().sync();

  // ---- Phase 3: streaming apply; block-stride over 4-row chunks ----
  const float4 w  = weight[tid];
  const float4 bb = bias[tid];
  const int n_chunks = n_rows >> 2;
  for (int c = blockIdx.x; c < n_chunks; c += gridDim.x) {
    const int row0 = c << 2;
    #pragma unroll
    for (int r = 0; r < 4; ++r) {
      const int row = row0 + r;
      const float2 gst = gstats[row / L];            // uniform broadcast
      const float gmu = gst.x, grs = gst.y;
      const float2 st = tstats[row];                 // raw {sum, sumsq}
      const float tmu = st.x * invD;
      const float trs = rsqrtf(st.y * invD - tmu * tmu + EPS) * 0.5f;

      const long base = (long)row * 256;
      const float4 v = x[base + tid];
      float4 o;
      o.x = ((v.x - gmu) * grs + (v.x - tmu) * trs) * w.x + bb.x;
      o.y = ((v.y - gmu) * grs + (v.y - tmu) * trs) * w.y + bb.y;
      o.z = ((v.z - gmu) * grs + (v.z - tmu) * trs) * w.z + bb.z;
      o.w = ((v.w - gmu) * grs + (v.w - tmu) * trs) * w.w + bb.w;
      out[base + tid] = o;
    }
  }
}

extern "C" void kernel_launch(void* const* d_in, const int* in_sizes, int n_in,
                              void* d_out, int out_size, void* d_ws, size_t ws_size,
                              hipStream_t stream) {
  const float4* x      = (const float4*)d_in[0];
  // d_in[1] = mask (G, T/G) int32 ones — only shape matters; G hardcoded = 5.
  const float4* weight = (const float4*)d_in[2];
  const float4* bias   = (const float4*)d_in[3];
  float4* out          = (float4*)d_out;

  const int D = in_sizes[2];                 // 1024
  const int T = in_sizes[1];                 // mask flat elems = T = 4000
  const int B = in_sizes[0] / (T * D);       // 8
  int L      = T / NUM_G;                    // 800
  int n_rows = B * T;                        // 32000
  const long Ng = (long)L * D;               // 819200 elems per group

  float2* tstats = (float2*)d_ws;            // n_rows float2
  float2* gstats = (float2*)((char*)d_ws + (size_t)n_rows * sizeof(float2));

  float invD  = 1.0f / (float)D;
  float invNg = 1.0f / (float)Ng;

  void* args[] = {(void*)&x, (void*)&weight, (void*)&bias, (void*)&out,
                  (void*)&tstats, (void*)&gstats,
                  (void*)&n_rows, (void*)&L, (void*)&invD, (void*)&invNg};
  hipLaunchCooperativeKernel((const void*)rfnorm_fused, dim3(NBLK), dim3(NTHR),
                             args, 0, stream);
}

// Round 3
// 251.685 us; speedup vs baseline: 2.3966x; 2.3966x over previous
//
#include <hip/hip_runtime.h>

// RFNorm: out = (0.5*groupnorm(x) + 0.5*tokennorm(x)) * weight + bias
// x: (B=8, T=4000, D=1024) fp32; G=5 contiguous groups of L=T/G tokens.
//
// R4 == R3 resubmit (R3 bench died in container acquisition, no data).
// 3 dispatches, zero atomics:
//   1. stats:   2 rows per wave (8 fp32x4 loads in flight/lane for MLP;
//               the two rows' shuffle trees interleave to hide DS latency).
//   2. greduce: one block per group reduces its 800 token sums.
//   3. out:     pure streaming elementwise map, 4 rows/block (x re-read is
//               L3-resident: R1 counters showed FETCH ~= 1x x-size total).

#define EPS 1e-5f
#define NUM_G 5

__global__ __launch_bounds__(256) void stats_kernel(
    const float4* __restrict__ x, float2* __restrict__ tstats) {
  const int wave = threadIdx.x >> 6, lane = threadIdx.x & 63;
  const int row0 = blockIdx.x * 8 + wave * 2;      // rows row0, row0+1
  const long b0 = (long)row0 * 256;

  float4 a[4], b[4];
  #pragma unroll
  for (int j = 0; j < 4; ++j) a[j] = x[b0 + lane + 64 * j];
  #pragma unroll
  for (int j = 0; j < 4; ++j) b[j] = x[b0 + 256 + lane + 64 * j];

  float s0 = 0.f, q0 = 0.f, s1 = 0.f, q1 = 0.f;
  #pragma unroll
  for (int j = 0; j < 4; ++j) {
    s0 += (a[j].x + a[j].y) + (a[j].z + a[j].w);
    q0 += (a[j].x * a[j].x + a[j].y * a[j].y) + (a[j].z * a[j].z + a[j].w * a[j].w);
    s1 += (b[j].x + b[j].y) + (b[j].z + b[j].w);
    q1 += (b[j].x * b[j].x + b[j].y * b[j].y) + (b[j].z * b[j].z + b[j].w * b[j].w);
  }
  #pragma unroll
  for (int off = 1; off < 64; off <<= 1) {
    s0 += __shfl_xor(s0, off, 64);  q0 += __shfl_xor(q0, off, 64);
    s1 += __shfl_xor(s1, off, 64);  q1 += __shfl_xor(q1, off, 64);
  }
  if (lane == 0) {
    float2 st0; st0.x = s0; st0.y = q0;
    float2 st1; st1.x = s1; st1.y = q1;
    tstats[row0]     = st0;
    tstats[row0 + 1] = st1;
  }
}

__global__ __launch_bounds__(256) void greduce_kernel(
    const float2* __restrict__ tstats, float2* __restrict__ gstats,
    int L, float invNg) {
  const int g = blockIdx.x;
  float s = 0.f, sq = 0.f;
  for (int j = threadIdx.x; j < L; j += 256) {
    float2 st = tstats[(long)g * L + j];
    s += st.x; sq += st.y;
  }
  #pragma unroll
  for (int off = 1; off < 64; off <<= 1) {
    s  += __shfl_xor(s,  off, 64);
    sq += __shfl_xor(sq, off, 64);
  }
  __shared__ float ls[4], lq[4];
  const int wave = threadIdx.x >> 6, lane = threadIdx.x & 63;
  if (lane == 0) { ls[wave] = s; lq[wave] = sq; }
  __syncthreads();
  if (threadIdx.x == 0) {
    const float S  = (ls[0] + ls[1]) + (ls[2] + ls[3]);
    const float SQ = (lq[0] + lq[1]) + (lq[2] + lq[3]);
    const float gmu = S * invNg;
    float2 o;
    o.x = gmu;
    o.y = rsqrtf(SQ * invNg - gmu * gmu + EPS) * 0.5f;  // fold RFN=0.5
    gstats[g] = o;
  }
}

__global__ __launch_bounds__(256) void out_kernel(
    const float4* __restrict__ x, const float2* __restrict__ gstats,
    const float2* __restrict__ tstats,
    const float4* __restrict__ weight, const float4* __restrict__ bias,
    float4* __restrict__ out, int L, float invD) {
  const int tid = threadIdx.x;
  const float4 w  = weight[tid];
  const float4 bb = bias[tid];
  const int row0 = blockIdx.x * 4;

  #pragma unroll
  for (int r = 0; r < 4; ++r) {
    const int row = row0 + r;
    const float2 gst = gstats[row / L];              // uniform per row
    const float gmu = gst.x, grs = gst.y;
    const float2 st = tstats[row];                   // raw {sum, sumsq}
    const float tmu = st.x * invD;
    const float trs = rsqrtf(st.y * invD - tmu * tmu + EPS) * 0.5f;

    const long base = (long)row * 256;
    const float4 v = x[base + tid];
    float4 o;
    o.x = ((v.x - gmu) * grs + (v.x - tmu) * trs) * w.x + bb.x;
    o.y = ((v.y - gmu) * grs + (v.y - tmu) * trs) * w.y + bb.y;
    o.z = ((v.z - gmu) * grs + (v.z - tmu) * trs) * w.z + bb.z;
    o.w = ((v.w - gmu) * grs + (v.w - tmu) * trs) * w.w + bb.w;
    out[base + tid] = o;
  }
}

extern "C" void kernel_launch(void* const* d_in, const int* in_sizes, int n_in,
                              void* d_out, int out_size, void* d_ws, size_t ws_size,
                              hipStream_t stream) {
  const float* x      = (const float*)d_in[0];
  // d_in[1] = mask (G, T/G) int32 ones — only shape matters; G hardcoded = 5.
  const float* weight = (const float*)d_in[2];
  const float* bias   = (const float*)d_in[3];
  float* out          = (float*)d_out;

  const int D = in_sizes[2];                 // 1024
  const int T = in_sizes[1];                 // mask flat elems = T = 4000
  const int B = in_sizes[0] / (T * D);       // 8
  const int L = T / NUM_G;                   // 800
  const int n_rows = B * T;                  // 32000
  const long Ng = (long)L * D;               // 819200 elems per group

  float2* tstats = (float2*)d_ws;                    // n_rows float2
  float2* gstats = (float2*)((char*)d_ws + (size_t)n_rows * sizeof(float2));

  dim3 blk(256);
  stats_kernel<<<dim3(n_rows / 8), blk, 0, stream>>>((const float4*)x, tstats);

  greduce_kernel<<<dim3(B * NUM_G), blk, 0, stream>>>(
      tstats, gstats, L, 1.0f / (float)Ng);

  out_kernel<<<dim3(n_rows / 4), blk, 0, stream>>>(
      (const float4*)x, gstats, tstats,
      (const float4*)weight, (const float4*)bias,
      (float4*)out, L, 1.0f / D);
}

// Round 4
// 248.340 us; speedup vs baseline: 2.4289x; 1.0135x over previous
//
#include <hip/hip_runtime.h>

// RFNorm: out = (0.5*groupnorm(x) + 0.5*tokennorm(x)) * weight + bias
// x: (B=8, T=4000, D=1024) fp32; G=5 contiguous groups of L=T/G tokens.
//
// R5: collapse 3 dispatches -> 2. Evidence: R1 showed ~168us of timed-region
// overhead that is not our kernels (512MB ws-poison fill ~77us/iter + launch
// path); R3 showed stats-pass MLP is not the bottleneck. Remaining lever is
// the 40-block greduce dispatch sitting as a full-width serialization point
// between the two streaming passes.
//   K1 stats: 2 rows/wave, 8 rows/block; writes tstats[row]={sum,sumsq} AND
//             one per-block group partial gpart[block] (LDS combine of 4 waves).
//   K2 out:   each block redundantly reduces its group's L/8=100 partials
//             (800B, L2-hot, overlapped across blocks) -> gmu/grs, then
//             streams 8 rows/block applying both norms.
// Group-sum reduction order changes (hierarchical vs strided) — fp32-harmless
// vs 0.03125 tolerance. Token-path arithmetic bit-identical to R0 baseline.

#define EPS 1e-5f
#define NUM_G 5

__global__ __launch_bounds__(256) void stats_kernel(
    const float4* __restrict__ x, float2* __restrict__ tstats,
    float2* __restrict__ gpart) {
  const int wave = threadIdx.x >> 6, lane = threadIdx.x & 63;
  const int row0 = blockIdx.x * 8 + wave * 2;      // rows row0, row0+1
  const long b0 = (long)row0 * 256;

  float4 a[4], b[4];
  #pragma unroll
  for (int j = 0; j < 4; ++j) a[j] = x[b0 + lane + 64 * j];
  #pragma unroll
  for (int j = 0; j < 4; ++j) b[j] = x[b0 + 256 + lane + 64 * j];

  float s0 = 0.f, q0 = 0.f, s1 = 0.f, q1 = 0.f;
  #pragma unroll
  for (int j = 0; j < 4; ++j) {
    s0 += (a[j].x + a[j].y) + (a[j].z + a[j].w);
    q0 += (a[j].x * a[j].x + a[j].y * a[j].y) + (a[j].z * a[j].z + a[j].w * a[j].w);
    s1 += (b[j].x + b[j].y) + (b[j].z + b[j].w);
    q1 += (b[j].x * b[j].x + b[j].y * b[j].y) + (b[j].z * b[j].z + b[j].w * b[j].w);
  }
  #pragma unroll
  for (int off = 1; off < 64; off <<= 1) {
    s0 += __shfl_xor(s0, off, 64);  q0 += __shfl_xor(q0, off, 64);
    s1 += __shfl_xor(s1, off, 64);  q1 += __shfl_xor(q1, off, 64);
  }

  __shared__ float ls[4], lq[4];
  if (lane == 0) {
    float2 st0; st0.x = s0; st0.y = q0;
    float2 st1; st1.x = s1; st1.y = q1;
    tstats[row0]     = st0;
    tstats[row0 + 1] = st1;
    ls[wave] = s0 + s1;
    lq[wave] = q0 + q1;
  }
  __syncthreads();
  if (threadIdx.x == 0) {
    float2 p;
    p.x = (ls[0] + ls[1]) + (ls[2] + ls[3]);
    p.y = (lq[0] + lq[1]) + (lq[2] + lq[3]);
    gpart[blockIdx.x] = p;
  }
}

__global__ __launch_bounds__(256) void out_kernel(
    const float4* __restrict__ x, const float2* __restrict__ tstats,
    const float2* __restrict__ gpart,
    const float4* __restrict__ weight, const float4* __restrict__ bias,
    float4* __restrict__ out, int ppg, int bpg, float invNg, float invD) {
  const int tid = threadIdx.x;
  const int wave = tid >> 6, lane = tid & 63;
  const int g = blockIdx.x / bpg;                  // group of this block

  // --- redundant per-block group reduce: ppg (=100) partials, L2-hot ---
  float s = 0.f, q = 0.f;
  for (int j = tid; j < ppg; j += 256) {
    float2 p = gpart[g * ppg + j];
    s += p.x; q += p.y;
  }
  #pragma unroll
  for (int off = 1; off < 64; off <<= 1) {
    s += __shfl_xor(s, off, 64);
    q += __shfl_xor(q, off, 64);
  }
  __shared__ float ls[4], lq[4], sg[2];
  if (lane == 0) { ls[wave] = s; lq[wave] = q; }
  __syncthreads();
  if (tid == 0) {
    const float S  = (ls[0] + ls[1]) + (ls[2] + ls[3]);
    const float SQ = (lq[0] + lq[1]) + (lq[2] + lq[3]);
    const float gmu = S * invNg;
    sg[0] = gmu;
    sg[1] = rsqrtf(SQ * invNg - gmu * gmu + EPS) * 0.5f;   // fold RFN=0.5
  }
  __syncthreads();
  const float gmu = sg[0], grs = sg[1];

  // --- streaming apply: 8 rows/block ---
  const float4 w  = weight[tid];
  const float4 bb = bias[tid];
  const int row0 = blockIdx.x * 8;

  #pragma unroll
  for (int r = 0; r < 8; ++r) {
    const int row = row0 + r;
    const float2 st = tstats[row];                 // raw {sum, sumsq}, broadcast
    const float tmu = st.x * invD;
    const float trs = rsqrtf(st.y * invD - tmu * tmu + EPS) * 0.5f;

    const long base = (long)row * 256;
    const float4 v = x[base + tid];
    float4 o;
    o.x = ((v.x - gmu) * grs + (v.x - tmu) * trs) * w.x + bb.x;
    o.y = ((v.y - gmu) * grs + (v.y - tmu) * trs) * w.y + bb.y;
    o.z = ((v.z - gmu) * grs + (v.z - tmu) * trs) * w.z + bb.z;
    o.w = ((v.w - gmu) * grs + (v.w - tmu) * trs) * w.w + bb.w;
    out[base + tid] = o;
  }
}

extern "C" void kernel_launch(void* const* d_in, const int* in_sizes, int n_in,
                              void* d_out, int out_size, void* d_ws, size_t ws_size,
                              hipStream_t stream) {
  const float* x      = (const float*)d_in[0];
  // d_in[1] = mask (G, T/G) int32 ones — only shape matters; G hardcoded = 5.
  const float* weight = (const float*)d_in[2];
  const float* bias   = (const float*)d_in[3];
  float* out          = (float*)d_out;

  const int D = in_sizes[2];                 // 1024
  const int T = in_sizes[1];                 // mask flat elems = T = 4000
  const int B = in_sizes[0] / (T * D);       // 8
  const int L = T / NUM_G;                   // 800
  const int n_rows = B * T;                  // 32000
  const long Ng = (long)L * D;               // 819200 elems per group

  float2* tstats = (float2*)d_ws;                    // n_rows float2
  float2* gpart  = (float2*)((char*)d_ws + (size_t)n_rows * sizeof(float2));

  const int ppg = L / 8;                     // stats blocks per group = 100
  const int bpg = L / 8;                     // out   blocks per group = 100

  dim3 blk(256);
  stats_kernel<<<dim3(n_rows / 8), blk, 0, stream>>>(
      (const float4*)x, tstats, gpart);

  out_kernel<<<dim3(n_rows / 8), blk, 0, stream>>>(
      (const float4*)x, tstats, gpart,
      (const float4*)weight, (const float4*)bias,
      (float4*)out, ppg, bpg, 1.0f / (float)Ng, 1.0f / D);
}